// Round 2
// baseline (2543.486 us; speedup 1.0000x reference)
//
#include <hip/hip_runtime.h>
#include <hip/hip_bf16.h>
#include <stdint.h>

typedef __bf16 bf16_t;
typedef __bf16 bf16x8 __attribute__((ext_vector_type(8)));
typedef float f32x4 __attribute__((ext_vector_type(4)));

#define LSTM_B 2048
#define LSTM_T 256
#define LSTM_H 256
#define LSTM_O 10
#define NBT 32      // batch tiles of 64 rows
#define NSL 8       // hidden slices of 32 cols
#define THREADS 512 // 8 waves: wave = (m = w&3 [M-tile], cg = w>>2 [16-col group])

// d_ws layout (needs ~4.72 MB)
#define WS_CNT   0            // 32 int counters (one per batch tile), memset to 0 each launch
#define WS_W2    1024         // 512 KB bf16 cast of Wh
#define WS_EXCH  525312       // 2 buffers x 32 bt x 32768 B (h exchange, bf16 [64][256])
#define WS_EXF   2622464      // 32 bt x 65536 B (final h fp32 [64][256])

__device__ __forceinline__ float sigmoid_f(float x) { return 1.0f / (1.0f + __expf(-x)); }
__device__ __forceinline__ float tanh_f(float x)    { return 2.0f / (1.0f + __expf(-2.0f * x)) - 1.0f; }
// XOR-swizzle on element index of h_sh [64][256] bf16: spreads A-frag rows across banks
__device__ __forceinline__ int hsw(int r, int k) { return (r * 256 + k) ^ ((r & 7) << 3); }

__device__ __forceinline__ unsigned int pack2(float a, float b) {
    unsigned short ua = __builtin_bit_cast(unsigned short, (bf16_t)a);
    unsigned short ub = __builtin_bit_cast(unsigned short, (bf16_t)b);
    return (unsigned int)ua | ((unsigned int)ub << 16);
}

__global__ void __launch_bounds__(256) cast_wh_kernel(const float* __restrict__ Wh,
                                                      bf16_t* __restrict__ W2) {
    int idx = (blockIdx.x * 256 + threadIdx.x) * 4;
    float4 v = *(const float4*)(Wh + idx);
    bf16_t o0 = (bf16_t)v.x, o1 = (bf16_t)v.y, o2 = (bf16_t)v.z, o3 = (bf16_t)v.w;
    bf16_t tmp[4] = {o0, o1, o2, o3};
    *(uint2*)(W2 + idx) = *(uint2*)tmp;
}

__global__ void __launch_bounds__(THREADS, 2) lstm_kernel(
    const float* __restrict__ x,     // [B, T]
    const float* __restrict__ Wx,    // [4*H]
    const float* __restrict__ bx,    // [4*H]
    const float* __restrict__ bh,    // [4*H]
    const float* __restrict__ W_ph,  // [O, H]
    const float* __restrict__ b_ph,  // [O]
    float* __restrict__ out,         // [B, O]
    char* __restrict__ ws)
{
    __shared__ __align__(16) bf16_t h_sh[64 * 256];   // full h_{t-1}, swizzled (32 KB)
    __shared__ __align__(16) float  x_sh[64 * 257];   // x tile, stride 257 vs bank conflicts (64.25 KB)

    int* cnt = (int*)(ws + WS_CNT);
    const bf16_t* W2 = (const bf16_t*)(ws + WS_W2);

    const int tid  = threadIdx.x;
    const int bt   = blockIdx.x & 31;   // batch tile; partners (same bt) land on same XCD (i%8)
    const int j    = blockIdx.x >> 5;   // hidden slice 0..7
    const int wave = tid >> 6;
    const int lane = tid & 63;
    const int n    = lane & 15;
    const int grp  = lane >> 4;
    const int m    = wave & 3;          // M-tile (rows m*16..m*16+15)
    const int cg   = wave >> 2;         // col group within slice
    const int hcol = j * 32 + cg * 16 + n;   // this lane's global hidden column
    const int b0   = bt * 64;

    // ---- one-time staging ----
    // x tile [64][256] fp32, coalesced
#pragma unroll
    for (int i = 0; i < 32; ++i) {
        int d = tid + i * 512;
        int row = d >> 8, col = d & 255;
        x_sh[row * 257 + col] = x[(size_t)(b0 + row) * 256 + col];
    }
    // zero h_sh
#pragma unroll
    for (int i = 0; i < 16; ++i) ((unsigned int*)h_sh)[tid + i * 512] = 0u;

    // weight slice -> registers: 4 gates x 8 k-chunks x 16B = 128 VGPRs
    bf16x8 bW[4][8];
#pragma unroll
    for (int g = 0; g < 4; ++g)
#pragma unroll
        for (int kk = 0; kk < 8; ++kk)
            bW[g][kk] = *(const bf16x8*)(W2 + ((size_t)(g * 256 + hcol)) * 256 + kk * 32 + grp * 8);

    float wxv[4], biv[4];
#pragma unroll
    for (int g = 0; g < 4; ++g) {
        wxv[g] = Wx[g * 256 + hcol];
        biv[g] = bx[g * 256 + hcol] + bh[g * 256 + hcol];
    }

    float c_st[4] = {0.f, 0.f, 0.f, 0.f};
    float hval[4];
    __syncthreads();

    for (int t = 0; t < LSTM_T; ++t) {
        // 1. A-frags from LDS (h_{t-1}): rows m*16+n, k = kk*32+grp*8
        bf16x8 aF[8];
#pragma unroll
        for (int kk = 0; kk < 8; ++kk)
            aF[kk] = *(const bf16x8*)&h_sh[hsw(m * 16 + n, kk * 32 + grp * 8)];

        // 2. MFMA: all weight operands in registers
        f32x4 acc[4];
#pragma unroll
        for (int g = 0; g < 4; ++g) acc[g] = (f32x4){0.f, 0.f, 0.f, 0.f};
#pragma unroll
        for (int g = 0; g < 4; ++g)
#pragma unroll
            for (int kk = 0; kk < 8; ++kk)
                acc[g] = __builtin_amdgcn_mfma_f32_16x16x32_bf16(aF[kk], bW[g][kk], acc[g], 0, 0, 0);

        // 3. pointwise: lane owns rows r = m*16+grp*4+q, col hcol
#pragma unroll
        for (int q = 0; q < 4; ++q) {
            int r = m * 16 + grp * 4 + q;
            float xt = x_sh[r * 257 + t];
            float z0 = acc[0][q] + xt * wxv[0] + biv[0];
            float z1 = acc[1][q] + xt * wxv[1] + biv[1];
            float z2 = acc[2][q] + xt * wxv[2] + biv[2];
            float z3 = acc[3][q] + xt * wxv[3] + biv[3];
            float gg = tanh_f(z0);
            float ii = sigmoid_f(z1);
            float ff = sigmoid_f(z2);
            float oo = sigmoid_f(z3);
            float cn = gg * ii + c_st[q] * ff;
            c_st[q] = cn;
            hval[q] = tanh_f(cn) * oo;
        }

        if (t < LSTM_T - 1) {
            // 4. pack own slice -> double-buffered global exchange (agent-scope atomics)
            unsigned long long* ebuf =
                (unsigned long long*)(ws + WS_EXCH + (size_t)((t & 1) * 32 + bt) * 32768);
            unsigned long long v64[4];
#pragma unroll
            for (int q = 0; q < 4; ++q) {
                float nb = __shfl_xor(hval[q], 1);
                unsigned int p01 = pack2(hval[q], nb);      // cols n, n+1 (valid on even n)
                unsigned int p23 = __shfl_xor(p01, 2);      // cols n+2, n+3
                v64[q] = (unsigned long long)p01 | ((unsigned long long)p23 << 32);
            }
            if ((lane & 3) == 0) {
#pragma unroll
                for (int q = 0; q < 4; ++q) {
                    int r = m * 16 + grp * 4 + q;
                    __hip_atomic_store(&ebuf[(r * 256 + hcol) >> 2], v64[q],
                                       __ATOMIC_RELAXED, __HIP_MEMORY_SCOPE_AGENT);
                }
            }
            // 5. barrier among the 8 slice-blocks of this batch tile
            __syncthreads();   // drains vmcnt -> stores globally visible
            if (tid == 0) {
                __hip_atomic_fetch_add(&cnt[bt], 1, __ATOMIC_RELEASE, __HIP_MEMORY_SCOPE_AGENT);
                while (__hip_atomic_load(&cnt[bt], __ATOMIC_ACQUIRE, __HIP_MEMORY_SCOPE_AGENT)
                       < NSL * (t + 1)) {}
            }
            __syncthreads();
            // 6. stage full h_t -> LDS (coherent loads bypass stale caches)
#pragma unroll
            for (int i = 0; i < 8; ++i) {
                int d = tid + i * 512;   // u64 index over [64][256] bf16
                unsigned long long v = __hip_atomic_load(&ebuf[d],
                                       __ATOMIC_RELAXED, __HIP_MEMORY_SCOPE_AGENT);
                int row = d >> 6;
                int e   = (d & 63) << 2;
                int s   = (row * 256 + e) ^ ((row & 7) << 3);
                *(unsigned long long*)((char*)h_sh + (size_t)s * 2) = v;
            }
            __syncthreads();
        }
    }

    // ---- final step: fp32 h_T exchange + fused projection ----
    float* exf = (float*)(ws + WS_EXF + (size_t)bt * 65536);   // [64][256] fp32
#pragma unroll
    for (int q = 0; q < 4; ++q) {
        int r = m * 16 + grp * 4 + q;
        __hip_atomic_store(&exf[r * 256 + hcol], hval[q],
                           __ATOMIC_RELAXED, __HIP_MEMORY_SCOPE_AGENT);
    }
    __syncthreads();
    if (tid == 0) {
        __hip_atomic_fetch_add(&cnt[bt], 1, __ATOMIC_RELEASE, __HIP_MEMORY_SCOPE_AGENT);
        while (__hip_atomic_load(&cnt[bt], __ATOMIC_ACQUIRE, __HIP_MEMORY_SCOPE_AGENT)
               < NSL * LSTM_T) {}
    }
    __syncthreads();

    // block j projects rows j*8 .. j*8+7; load those fp32 h rows into x_sh
#pragma unroll
    for (int i = 0; i < 4; ++i) {
        int d = tid + i * 512;          // 2048 dwords = 8 rows x 256
        int rr = d >> 8, col = d & 255;
        float v = __hip_atomic_load(&exf[(j * 8 + rr) * 256 + col],
                                    __ATOMIC_RELAXED, __HIP_MEMORY_SCOPE_AGENT);
        x_sh[rr * 257 + col] = v;
    }
    __syncthreads();

    if (tid < 8 * LSTM_O) {
        int rr = tid & 7;
        int o  = tid >> 3;
        const float* wrow = W_ph + o * 256;
        float s = 0.f;
#pragma unroll 4
        for (int k0 = 0; k0 < 256; ++k0) {
            int k = (k0 + rr * 32) & 255;   // rotate start vs LDS bank conflicts
            s += x_sh[rr * 257 + k] * wrow[k];
        }
        out[(size_t)(b0 + j * 8 + rr) * LSTM_O + o] = s + b_ph[o];
    }
}

extern "C" void kernel_launch(void* const* d_in, const int* in_sizes, int n_in,
                              void* d_out, int out_size, void* d_ws, size_t ws_size,
                              hipStream_t stream) {
    const float* x    = (const float*)d_in[0];
    const float* Wx   = (const float*)d_in[1];
    const float* bx   = (const float*)d_in[2];
    const float* Wh   = (const float*)d_in[3];
    const float* bh   = (const float*)d_in[4];
    const float* W_ph = (const float*)d_in[5];
    const float* b_ph = (const float*)d_in[6];
    float* out = (float*)d_out;
    char* ws   = (char*)d_ws;

    hipMemsetAsync(ws + WS_CNT, 0, 128, stream);                       // zero barrier counters
    cast_wh_kernel<<<256, 256, 0, stream>>>(Wh, (bf16_t*)(ws + WS_W2));
    lstm_kernel<<<NBT * NSL, THREADS, 0, stream>>>(x, Wx, bx, bh, W_ph, b_ph, out, ws);
}